// Round 2
// baseline (392.370 us; speedup 1.0000x reference)
//
#include <hip/hip_runtime.h>

// Problem constants
#define DD   768      // appearance dim
#define NH   8        // heads
#define DKh  96       // key/geo dim

typedef __attribute__((ext_vector_type(8))) short short8;   // 8 bf16
typedef __attribute__((ext_vector_type(4))) float f32x4;

__device__ __forceinline__ unsigned short f2bf(float x) {
    union { float f; unsigned int u; } v; v.f = x;
    unsigned int r = v.u + 0x7FFFu + ((v.u >> 16) & 1u);   // RNE
    return (unsigned short)(r >> 16);
}

// ---------------- 1. merged convert: f_a fp32->bf16  AND  W[K|Q|V] -> bf16 [col][d] ----------------
__global__ __launch_bounds__(256) void k_cvt(const float* __restrict__ fa,
                                             unsigned short* __restrict__ abf,
                                             const float* __restrict__ wk,
                                             const float* __restrict__ wq,
                                             const float* __restrict__ wv,
                                             unsigned short* __restrict__ wbf) {
    __shared__ float ls[64 * 97];                      // used by W path only
    int bid = blockIdx.x;
    int t = threadIdx.x;
    if (bid < 1536) {                                  // ---- A path: 393216 float4 exactly
        int idx = bid * 256 + t;
        float4 v = ((const float4*)fa)[idx];
        ushort4 o;
        o.x = f2bf(v.x); o.y = f2bf(v.y); o.z = f2bf(v.z); o.w = f2bf(v.w);
        ((ushort4*)abf)[idx] = o;
        return;
    }
    // ---- W path: 288 blocks
    int wb = bid - 1536;
    int pid = wb / 12;                                 // 0..23 = (p,h)
    int db  = wb % 12;                                 // d-block of 64
    int p = pid >> 3, h = pid & 7;
    const float* src = (p == 0 ? wk : p == 1 ? wq : wv) + h * DD * DKh + db * 64 * DKh;
#pragma unroll
    for (int i = 0; i < 24; ++i) {                     // 64 rows x 96, coalesced
        int f = t + 256 * i;
        int dl = f / 96, e = f - dl * 96;
        ls[dl * 97 + e] = src[f];
    }
    __syncthreads();
    unsigned short* dst = wbf + (p * 768 + h * 96) * DD + db * 64;
#pragma unroll
    for (int i = 0; i < 24; ++i) {
        int f = t + 256 * i;
        int e = f >> 6, dl = f & 63;
        dst[e * DD + dl] = f2bf(ls[dl * 97 + e]);
    }
}

// ---------------- 2. projections: C[2048x2304] = A x W, MFMA bf16 ----------------
__global__ __launch_bounds__(256) void k_proj(const unsigned short* __restrict__ abf,
                                              const unsigned short* __restrict__ wbf,
                                              const float* __restrict__ wkb,
                                              const float* __restrict__ wqb,
                                              const float* __restrict__ wvb,
                                              unsigned short* __restrict__ kb,
                                              unsigned short* __restrict__ qb,
                                              unsigned short* __restrict__ vt) {
    int w = threadIdx.x >> 6, lane = threadIdx.x & 63;
    int lrow = lane & 15, quad = lane >> 4;
    int rt = blockIdx.x / 36, cg = blockIdx.x % 36;    // 32 row-tiles x 36 col-tiles
    int r0 = rt * 64 + w * 16;                         // wave: 16 rows x 64 cols
    int c0 = cg * 64;
    f32x4 z = {0.f, 0.f, 0.f, 0.f};
    f32x4 acc[4] = {z, z, z, z};
    for (int kk = 0; kk < DD; kk += 32) {
        short8 a = *(const short8*)(abf + (r0 + lrow) * DD + kk + quad * 8);
#pragma unroll
        for (int tt = 0; tt < 4; ++tt) {
            short8 b = *(const short8*)(wbf + (c0 + tt * 16 + lrow) * DD + kk + quad * 8);
            acc[tt] = __builtin_amdgcn_mfma_f32_16x16x32_bf16(a, b, acc[tt], 0, 0, 0);
        }
    }
    int rbase = r0 + quad * 4;
    int b_ = rbase >> 8, mbase = rbase & 255;
#pragma unroll
    for (int tt = 0; tt < 4; ++tt) {
        int cc = c0 + tt * 16 + lrow;
        int p = cc / 768, rm = cc - p * 768;
        int h = rm / 96,  e = rm - h * 96;
        float bias = (p == 0 ? wkb : p == 1 ? wqb : wvb)[h * 96 + e];
        if (p == 2) {                                  // V transposed: [e][m], m packed x4
            ushort4 v4;
            v4.x = f2bf(acc[tt][0] + bias);
            v4.y = f2bf(acc[tt][1] + bias);
            v4.z = f2bf(acc[tt][2] + bias);
            v4.w = f2bf(acc[tt][3] + bias);
            *(ushort4*)(vt + ((b_ * 8 + h) * 96 + e) * 256 + mbase) = v4;
        } else {
            float sc = (p == 1) ? 0.10206207261596577f : 1.0f;   // fold 1/sqrt(96) into Q
            unsigned short* dst = (p == 0 ? kb : qb) + ((b_ * 8 + h) * 256 + mbase) * 96 + e;
#pragma unroll
            for (int r = 0; r < 4; ++r)
                dst[r * 96] = f2bf((acc[tt][r] + bias) * sc);
        }
    }
}

// ---------------- 3. FUSED geometric bias + scores -> Lt[b,h,n,m] ----------------
// Block = (b, 16m x 16n). NO pe LDS staging: each pe element feeds exactly one
// MFMA A-fragment element, and the fragment layout (16 rows x 128B contiguous
// per load) is already dense/coalesced against global pe. LDS = stot only
// (8 KB, stride 257 -> conflict-free writes), one barrier. Occupancy 2 -> ~5
// blocks/CU for better latency hiding of the 201 MB pe stream.
// Phase A: wg = pe x WG^T via MFMA (WG^T frags built per-lane from global);
//          log(max(.,1e-6)) -> stot LDS.
// Phase B: scores K.Q^T per head via MFMA, add stot, write Lt[b,h,n,m]
//          as one f32x4 per lane.
__global__ __launch_bounds__(256) void k_wgs(const float* __restrict__ pe,
                                             const float* __restrict__ wgw,
                                             const float* __restrict__ wgb,
                                             const unsigned short* __restrict__ kb,
                                             const unsigned short* __restrict__ qb,
                                             float* __restrict__ Lt) {
    __shared__ float stot[8 * 257];                    // [h][mi*16+ni], padded
    int bi = blockIdx.x;
    int b = bi >> 8, mt = (bi >> 4) & 15, nt = bi & 15;
    int m0 = mt * 16, n0 = nt * 16;
    int t = threadIdx.x;
    int w = t >> 6, lane = t & 63, lrow = lane & 15, quad = lane >> 4;
    // ---- WG^T fragments direct from global: col = lrow (cols 8..15 zero)
    short8 bf[3];
    if (lrow < 8) {
#pragma unroll
        for (int ks = 0; ks < 3; ++ks) {
            const float* wp = wgw + lrow * 96 + ks * 32 + quad * 8;
            float4 w0 = *(const float4*)wp;
            float4 w1 = *(const float4*)(wp + 4);
            short8 bb;
            bb[0] = f2bf(w0.x); bb[1] = f2bf(w0.y); bb[2] = f2bf(w0.z); bb[3] = f2bf(w0.w);
            bb[4] = f2bf(w1.x); bb[5] = f2bf(w1.y); bb[6] = f2bf(w1.z); bb[7] = f2bf(w1.w);
            bf[ks] = bb;
        }
    } else {
        short8 zz8 = {0, 0, 0, 0, 0, 0, 0, 0};
        bf[0] = zz8; bf[1] = zz8; bf[2] = zz8;
    }
    float gbias = wgb[lrow & 7];
    // ---- Phase A: wg MFMA, A-frags straight from global pe (f32 -> bf16)
    const float* peb0 = pe + (((size_t)b * 256 + m0) * 256 + n0) * 96;
#pragma unroll
    for (int rt4 = 0; rt4 < 4; ++rt4) {
        int rt = w * 4 + rt4;
        int p = rt * 16 + lrow;                        // pair index 0..255
        const float* pr = peb0 + (size_t)(p >> 4) * 24576 + (p & 15) * 96;
        f32x4 acc = {0.f, 0.f, 0.f, 0.f};
#pragma unroll
        for (int ks = 0; ks < 3; ++ks) {
            const float* ap = pr + ks * 32 + quad * 8;
            float4 v0 = *(const float4*)ap;
            float4 v1 = *(const float4*)(ap + 4);
            short8 a;
            a[0] = f2bf(v0.x); a[1] = f2bf(v0.y); a[2] = f2bf(v0.z); a[3] = f2bf(v0.w);
            a[4] = f2bf(v1.x); a[5] = f2bf(v1.y); a[6] = f2bf(v1.z); a[7] = f2bf(v1.w);
            acc = __builtin_amdgcn_mfma_f32_16x16x32_bf16(a, bf[ks], acc, 0, 0, 0);
        }
        if (lrow < 8) {                                // col = h = lrow; row = rt*16+quad*4+r
#pragma unroll
            for (int r = 0; r < 4; ++r)
                stot[lrow * 257 + rt * 16 + quad * 4 + r] =
                    __logf(fmaxf(acc[r] + gbias, 1e-6f));
        }
    }
    __syncthreads();
    // ---- Phase B: scores, heads h = 2w, 2w+1
#pragma unroll
    for (int hh = 0; hh < 2; ++hh) {
        int h = w * 2 + hh;
        const unsigned short* ka = kb + ((size_t)((b * 8 + h) * 256) + m0 + lrow) * 96 + quad * 8;
        const unsigned short* qa = qb + ((size_t)((b * 8 + h) * 256) + n0 + lrow) * 96 + quad * 8;
        f32x4 acc = {0.f, 0.f, 0.f, 0.f};
#pragma unroll
        for (int ks = 0; ks < 3; ++ks) {
            short8 a  = *(const short8*)(ka + ks * 32);
            short8 bq = *(const short8*)(qa + ks * 32);
            acc = __builtin_amdgcn_mfma_f32_16x16x32_bf16(a, bq, acc, 0, 0, 0);
        }
        // D[m = quad*4+r][n = lrow] -> Lt[b,h, n0+lrow, m0+quad*4 .. +3] as f32x4
        f32x4 ov;
#pragma unroll
        for (int r = 0; r < 4; ++r)
            ov[r] = acc[r] + stot[h * 257 + (quad * 4 + r) * 16 + lrow];
        *(f32x4*)(Lt + ((size_t)((b * 8 + h) * 256) + n0 + lrow) * 256 + m0 + quad * 4) = ov;
    }
}

// ---------------- 4. FUSED softmax(over m) + P.V + residual ----------------
// Block = (b,h, 32-row n-tile). Phase 1: each wave softmaxes 8 contiguous
// Lt rows (1 float4/lane = full 1 KB row per wave-load), normalized bf16 P
// -> LDS [32][264] (pad 264: +8 shorts -> 2-way-max bank aliasing).
// Phase 2: out[n][e] = P[n][:] . V[e][:] via MFMA, + f_a residual.
__global__ __launch_bounds__(256) void k_smv(const float* __restrict__ Lt,
                                             const unsigned short* __restrict__ vt,
                                             const float* __restrict__ fa,
                                             float* __restrict__ out) {
    __shared__ unsigned short P[32 * 264];             // 16.5 KB
    int bid = blockIdx.x;                              // 512 = 64 bh x 8 nt
    int bh = bid >> 3, nt = bid & 7;
    int n0 = nt * 32;
    int t = threadIdx.x, w = t >> 6, lane = t & 63;
    const float* lb = Lt + ((size_t)bh * 256 + n0) * 256;
#pragma unroll
    for (int rr = 0; rr < 8; ++rr) {
        int row = w * 8 + rr;
        float4 v = *((const float4*)(lb + row * 256) + lane);
        float mx = fmaxf(fmaxf(v.x, v.y), fmaxf(v.z, v.w));
#pragma unroll
        for (int d = 1; d < 64; d <<= 1) mx = fmaxf(mx, __shfl_xor(mx, d));
        float e0 = __expf(v.x - mx), e1 = __expf(v.y - mx),
              e2 = __expf(v.z - mx), e3 = __expf(v.w - mx);
        float s = e0 + e1 + e2 + e3;
#pragma unroll
        for (int d = 1; d < 64; d <<= 1) s += __shfl_xor(s, d);
        float inv = 1.0f / s;
        ushort4 o;
        o.x = f2bf(e0 * inv); o.y = f2bf(e1 * inv);
        o.z = f2bf(e2 * inv); o.w = f2bf(e3 * inv);
        *(ushort4*)(P + row * 264 + lane * 4) = o;
    }
    __syncthreads();
    int lrow = lane & 15, quad = lane >> 4;
    int nsub = (w & 1) * 16, eb = (w >> 1) * 48;       // wave: 16 n x 48 e
    f32x4 zz = {0.f, 0.f, 0.f, 0.f};
    f32x4 acc[3] = {zz, zz, zz};
    const unsigned short* vb = vt + ((size_t)bh * 96 + eb + lrow) * 256 + quad * 8;
    const unsigned short* pb = P + (nsub + lrow) * 264 + quad * 8;
#pragma unroll
    for (int mk = 0; mk < 256; mk += 32) {
        short8 a = *(const short8*)(pb + mk);
#pragma unroll
        for (int tt = 0; tt < 3; ++tt) {
            short8 b = *(const short8*)(vb + tt * 16 * 256 + mk);
            acc[tt] = __builtin_amdgcn_mfma_f32_16x16x32_bf16(a, b, acc[tt], 0, 0, 0);
        }
    }
    int b_ = bh >> 3, h = bh & 7;
#pragma unroll
    for (int tt = 0; tt < 3; ++tt) {
        int idx = (b_ * 256 + n0 + nsub + quad * 4) * 768 + h * 96 + eb + tt * 16 + lrow;
#pragma unroll
        for (int r = 0; r < 4; ++r)
            out[idx + r * 768] = acc[tt][r] + fa[idx + r * 768];
    }
}

extern "C" void kernel_launch(void* const* d_in, const int* in_sizes, int n_in,
                              void* d_out, int out_size, void* d_ws, size_t ws_size,
                              hipStream_t stream) {
    const float* fa  = (const float*)d_in[0];
    const float* pe  = (const float*)d_in[1];
    const float* wgw = (const float*)d_in[2];
    const float* wgb = (const float*)d_in[3];
    const float* wkw = (const float*)d_in[4];
    const float* wkb = (const float*)d_in[5];
    const float* wqw = (const float*)d_in[6];
    const float* wqb = (const float*)d_in[7];
    const float* wvw = (const float*)d_in[8];
    const float* wvb = (const float*)d_in[9];
    float* out = (float*)d_out;
    char* ws = (char*)d_ws;
    unsigned short* abf = (unsigned short*)(ws);              // 2048*768 bf16
    unsigned short* wbf = (unsigned short*)(ws + 3145728);    // 2304*768 bf16
    unsigned short* kb  = (unsigned short*)(ws + 6684672);    // [b,h,m,e] bf16
    unsigned short* qb  = (unsigned short*)(ws + 9830400);    // [b,h,n,e] bf16 (scaled)
    unsigned short* vt  = (unsigned short*)(ws + 12976128);   // [b,h,e,m] bf16
    float*          Lt  = (float*)(ws + 16121856);            // [b,h,n,m] f32

    k_cvt <<<1824, 256, 0, stream>>>(fa, abf, wkw, wqw, wvw, wbf);
    k_proj<<<1152, 256, 0, stream>>>(abf, wbf, wkb, wqb, wvb, kb, qb, vt);
    k_wgs <<<2048, 256, 0, stream>>>(pe, wgw, wgb, kb, qb, Lt);
    k_smv <<< 512, 256, 0, stream>>>(Lt, vt, fa, out);
}

// Round 3
// 372.347 us; speedup vs baseline: 1.0538x; 1.0538x over previous
//
#include <hip/hip_runtime.h>

// Problem constants
#define DD   768      // appearance dim
#define NH   8        // heads
#define DKh  96       // key/geo dim

typedef __attribute__((ext_vector_type(8))) short short8;   // 8 bf16
typedef __attribute__((ext_vector_type(4))) float f32x4;

__device__ __forceinline__ unsigned short f2bf(float x) {
    union { float f; unsigned int u; } v; v.f = x;
    unsigned int r = v.u + 0x7FFFu + ((v.u >> 16) & 1u);   // RNE
    return (unsigned short)(r >> 16);
}

// ---------------- 1. merged convert: f_a fp32->bf16  AND  W[K|Q|V] -> bf16 [col][d] ----------------
__global__ __launch_bounds__(256) void k_cvt(const float* __restrict__ fa,
                                             unsigned short* __restrict__ abf,
                                             const float* __restrict__ wk,
                                             const float* __restrict__ wq,
                                             const float* __restrict__ wv,
                                             unsigned short* __restrict__ wbf) {
    __shared__ float ls[64 * 97];                      // used by W path only
    int bid = blockIdx.x;
    int t = threadIdx.x;
    if (bid < 1536) {                                  // ---- A path: 393216 float4 exactly
        int idx = bid * 256 + t;
        float4 v = ((const float4*)fa)[idx];
        ushort4 o;
        o.x = f2bf(v.x); o.y = f2bf(v.y); o.z = f2bf(v.z); o.w = f2bf(v.w);
        ((ushort4*)abf)[idx] = o;
        return;
    }
    // ---- W path: 288 blocks
    int wb = bid - 1536;
    int pid = wb / 12;                                 // 0..23 = (p,h)
    int db  = wb % 12;                                 // d-block of 64
    int p = pid >> 3, h = pid & 7;
    const float* src = (p == 0 ? wk : p == 1 ? wq : wv) + h * DD * DKh + db * 64 * DKh;
#pragma unroll
    for (int i = 0; i < 24; ++i) {                     // 64 rows x 96, coalesced
        int f = t + 256 * i;
        int dl = f / 96, e = f - dl * 96;
        ls[dl * 97 + e] = src[f];
    }
    __syncthreads();
    unsigned short* dst = wbf + (p * 768 + h * 96) * DD + db * 64;
#pragma unroll
    for (int i = 0; i < 24; ++i) {
        int f = t + 256 * i;
        int e = f >> 6, dl = f & 63;
        dst[e * DD + dl] = f2bf(ls[dl * 97 + e]);
    }
}

// ---------------- 2. projections: C[2048x2304] = A x W, MFMA bf16 ----------------
// Block = 128x128 (2x2 waves of 64x64). MFMA:VMEM = 16:8 per K-step,
// distinct L1 bytes 1.0 B/elem (was 3.0 at 64x64). 16 independent MFMAs of
// ILP per wave per step hides L2-hit latency at ~1 block/CU. Accumulation
// order per output element is identical to the 64x64 version (bitwise-same C).
__global__ __launch_bounds__(256) void k_proj(const unsigned short* __restrict__ abf,
                                              const unsigned short* __restrict__ wbf,
                                              const float* __restrict__ wkb,
                                              const float* __restrict__ wqb,
                                              const float* __restrict__ wvb,
                                              unsigned short* __restrict__ kb,
                                              unsigned short* __restrict__ qb,
                                              unsigned short* __restrict__ vt) {
    int w = threadIdx.x >> 6, lane = threadIdx.x & 63;
    int lrow = lane & 15, quad = lane >> 4;
    int rt = blockIdx.x / 18, cg = blockIdx.x % 18;    // 16 row-tiles x 18 col-tiles
    int r0 = rt * 128 + (w >> 1) * 64;                 // wave: 64 rows x 64 cols
    int c0 = cg * 128 + (w & 1) * 64;
    f32x4 z = {0.f, 0.f, 0.f, 0.f};
    f32x4 acc[4][4] = {{z, z, z, z}, {z, z, z, z}, {z, z, z, z}, {z, z, z, z}};
    for (int kk = 0; kk < DD; kk += 32) {
        short8 a[4], b[4];
#pragma unroll
        for (int i = 0; i < 4; ++i) {
            a[i] = *(const short8*)(abf + (r0 + i * 16 + lrow) * DD + kk + quad * 8);
            b[i] = *(const short8*)(wbf + (c0 + i * 16 + lrow) * DD + kk + quad * 8);
        }
#pragma unroll
        for (int mi = 0; mi < 4; ++mi)
#pragma unroll
            for (int ni = 0; ni < 4; ++ni)
                acc[mi][ni] = __builtin_amdgcn_mfma_f32_16x16x32_bf16(a[mi], b[ni], acc[mi][ni], 0, 0, 0);
    }
#pragma unroll
    for (int mi = 0; mi < 4; ++mi) {
        int rbase = r0 + mi * 16 + quad * 4;
        int b_ = rbase >> 8, mbase = rbase & 255;
#pragma unroll
        for (int ni = 0; ni < 4; ++ni) {
            int cc = c0 + ni * 16 + lrow;
            int p = cc / 768, rm = cc - p * 768;
            int h = rm / 96,  e = rm - h * 96;
            float bias = (p == 0 ? wkb : p == 1 ? wqb : wvb)[h * 96 + e];
            if (p == 2) {                              // V transposed: [e][m], m packed x4
                ushort4 v4;
                v4.x = f2bf(acc[mi][ni][0] + bias);
                v4.y = f2bf(acc[mi][ni][1] + bias);
                v4.z = f2bf(acc[mi][ni][2] + bias);
                v4.w = f2bf(acc[mi][ni][3] + bias);
                *(ushort4*)(vt + ((b_ * 8 + h) * 96 + e) * 256 + mbase) = v4;
            } else {
                float sc = (p == 1) ? 0.10206207261596577f : 1.0f;   // fold 1/sqrt(96) into Q
                unsigned short* dst = (p == 0 ? kb : qb) + ((b_ * 8 + h) * 256 + mbase) * 96 + e;
#pragma unroll
                for (int r = 0; r < 4; ++r)
                    dst[r * 96] = f2bf((acc[mi][ni][r] + bias) * sc);
            }
        }
    }
}

// ---------------- 3. FUSED geometric bias + scores -> Lt[b,h,n,m] ----------------
// Block = (b, 16m x 16n). NO pe LDS staging: each pe element feeds exactly one
// MFMA A-fragment element, and the fragment layout (16 rows x 128B contiguous
// per load) is already dense/coalesced against global pe. LDS = stot only
// (8 KB, stride 257 -> conflict-free), one barrier. BW-bound on the 201 MB
// pe stream (~32 us floor).
__global__ __launch_bounds__(256) void k_wgs(const float* __restrict__ pe,
                                             const float* __restrict__ wgw,
                                             const float* __restrict__ wgb,
                                             const unsigned short* __restrict__ kb,
                                             const unsigned short* __restrict__ qb,
                                             float* __restrict__ Lt) {
    __shared__ float stot[8 * 257];                    // [h][mi*16+ni], padded
    int bi = blockIdx.x;
    int b = bi >> 8, mt = (bi >> 4) & 15, nt = bi & 15;
    int m0 = mt * 16, n0 = nt * 16;
    int t = threadIdx.x;
    int w = t >> 6, lane = t & 63, lrow = lane & 15, quad = lane >> 4;
    // ---- WG^T fragments direct from global: col = lrow (cols 8..15 zero)
    short8 bf[3];
    if (lrow < 8) {
#pragma unroll
        for (int ks = 0; ks < 3; ++ks) {
            const float* wp = wgw + lrow * 96 + ks * 32 + quad * 8;
            float4 w0 = *(const float4*)wp;
            float4 w1 = *(const float4*)(wp + 4);
            short8 bb;
            bb[0] = f2bf(w0.x); bb[1] = f2bf(w0.y); bb[2] = f2bf(w0.z); bb[3] = f2bf(w0.w);
            bb[4] = f2bf(w1.x); bb[5] = f2bf(w1.y); bb[6] = f2bf(w1.z); bb[7] = f2bf(w1.w);
            bf[ks] = bb;
        }
    } else {
        short8 zz8 = {0, 0, 0, 0, 0, 0, 0, 0};
        bf[0] = zz8; bf[1] = zz8; bf[2] = zz8;
    }
    float gbias = wgb[lrow & 7];
    // ---- Phase A: wg MFMA, A-frags straight from global pe (f32 -> bf16)
    const float* peb0 = pe + (((size_t)b * 256 + m0) * 256 + n0) * 96;
#pragma unroll
    for (int rt4 = 0; rt4 < 4; ++rt4) {
        int rt = w * 4 + rt4;
        int p = rt * 16 + lrow;                        // pair index 0..255
        const float* pr = peb0 + (size_t)(p >> 4) * 24576 + (p & 15) * 96;
        f32x4 acc = {0.f, 0.f, 0.f, 0.f};
#pragma unroll
        for (int ks = 0; ks < 3; ++ks) {
            const float* ap = pr + ks * 32 + quad * 8;
            float4 v0 = *(const float4*)ap;
            float4 v1 = *(const float4*)(ap + 4);
            short8 a;
            a[0] = f2bf(v0.x); a[1] = f2bf(v0.y); a[2] = f2bf(v0.z); a[3] = f2bf(v0.w);
            a[4] = f2bf(v1.x); a[5] = f2bf(v1.y); a[6] = f2bf(v1.z); a[7] = f2bf(v1.w);
            acc = __builtin_amdgcn_mfma_f32_16x16x32_bf16(a, bf[ks], acc, 0, 0, 0);
        }
        if (lrow < 8) {                                // col = h = lrow; row = rt*16+quad*4+r
#pragma unroll
            for (int r = 0; r < 4; ++r)
                stot[lrow * 257 + rt * 16 + quad * 4 + r] =
                    __logf(fmaxf(acc[r] + gbias, 1e-6f));
        }
    }
    __syncthreads();
    // ---- Phase B: scores, heads h = 2w, 2w+1
#pragma unroll
    for (int hh = 0; hh < 2; ++hh) {
        int h = w * 2 + hh;
        const unsigned short* ka = kb + ((size_t)((b * 8 + h) * 256) + m0 + lrow) * 96 + quad * 8;
        const unsigned short* qa = qb + ((size_t)((b * 8 + h) * 256) + n0 + lrow) * 96 + quad * 8;
        f32x4 acc = {0.f, 0.f, 0.f, 0.f};
#pragma unroll
        for (int ks = 0; ks < 3; ++ks) {
            short8 a  = *(const short8*)(ka + ks * 32);
            short8 bq = *(const short8*)(qa + ks * 32);
            acc = __builtin_amdgcn_mfma_f32_16x16x32_bf16(a, bq, acc, 0, 0, 0);
        }
        // D[m = quad*4+r][n = lrow] -> Lt[b,h, n0+lrow, m0+quad*4 .. +3] as f32x4
        f32x4 ov;
#pragma unroll
        for (int r = 0; r < 4; ++r)
            ov[r] = acc[r] + stot[h * 257 + (quad * 4 + r) * 16 + lrow];
        *(f32x4*)(Lt + ((size_t)((b * 8 + h) * 256) + n0 + lrow) * 256 + m0 + quad * 4) = ov;
    }
}

// ---------------- 4. FUSED softmax(over m) + P.V + residual ----------------
// Block = (b,h, 32-row n-tile). Phase 1: each wave softmaxes 8 contiguous
// Lt rows (1 float4/lane = full 1 KB row per wave-load), normalized bf16 P
// -> LDS [32][264] (pad 264: +8 shorts -> 2-way-max bank aliasing).
// Phase 2: out[n][e] = P[n][:] . V[e][:] via MFMA, + f_a residual.
__global__ __launch_bounds__(256) void k_smv(const float* __restrict__ Lt,
                                             const unsigned short* __restrict__ vt,
                                             const float* __restrict__ fa,
                                             float* __restrict__ out) {
    __shared__ unsigned short P[32 * 264];             // 16.5 KB
    int bid = blockIdx.x;                              // 512 = 64 bh x 8 nt
    int bh = bid >> 3, nt = bid & 7;
    int n0 = nt * 32;
    int t = threadIdx.x, w = t >> 6, lane = t & 63;
    const float* lb = Lt + ((size_t)bh * 256 + n0) * 256;
#pragma unroll
    for (int rr = 0; rr < 8; ++rr) {
        int row = w * 8 + rr;
        float4 v = *((const float4*)(lb + row * 256) + lane);
        float mx = fmaxf(fmaxf(v.x, v.y), fmaxf(v.z, v.w));
#pragma unroll
        for (int d = 1; d < 64; d <<= 1) mx = fmaxf(mx, __shfl_xor(mx, d));
        float e0 = __expf(v.x - mx), e1 = __expf(v.y - mx),
              e2 = __expf(v.z - mx), e3 = __expf(v.w - mx);
        float s = e0 + e1 + e2 + e3;
#pragma unroll
        for (int d = 1; d < 64; d <<= 1) s += __shfl_xor(s, d);
        float inv = 1.0f / s;
        ushort4 o;
        o.x = f2bf(e0 * inv); o.y = f2bf(e1 * inv);
        o.z = f2bf(e2 * inv); o.w = f2bf(e3 * inv);
        *(ushort4*)(P + row * 264 + lane * 4) = o;
    }
    __syncthreads();
    int lrow = lane & 15, quad = lane >> 4;
    int nsub = (w & 1) * 16, eb = (w >> 1) * 48;       // wave: 16 n x 48 e
    f32x4 zz = {0.f, 0.f, 0.f, 0.f};
    f32x4 acc[3] = {zz, zz, zz};
    const unsigned short* vb = vt + ((size_t)bh * 96 + eb + lrow) * 256 + quad * 8;
    const unsigned short* pb = P + (nsub + lrow) * 264 + quad * 8;
#pragma unroll
    for (int mk = 0; mk < 256; mk += 32) {
        short8 a = *(const short8*)(pb + mk);
#pragma unroll
        for (int tt = 0; tt < 3; ++tt) {
            short8 b = *(const short8*)(vb + tt * 16 * 256 + mk);
            acc[tt] = __builtin_amdgcn_mfma_f32_16x16x32_bf16(a, b, acc[tt], 0, 0, 0);
        }
    }
    int b_ = bh >> 3, h = bh & 7;
#pragma unroll
    for (int tt = 0; tt < 3; ++tt) {
        int idx = (b_ * 256 + n0 + nsub + quad * 4) * 768 + h * 96 + eb + tt * 16 + lrow;
#pragma unroll
        for (int r = 0; r < 4; ++r)
            out[idx + r * 768] = acc[tt][r] + fa[idx + r * 768];
    }
}

extern "C" void kernel_launch(void* const* d_in, const int* in_sizes, int n_in,
                              void* d_out, int out_size, void* d_ws, size_t ws_size,
                              hipStream_t stream) {
    const float* fa  = (const float*)d_in[0];
    const float* pe  = (const float*)d_in[1];
    const float* wgw = (const float*)d_in[2];
    const float* wgb = (const float*)d_in[3];
    const float* wkw = (const float*)d_in[4];
    const float* wkb = (const float*)d_in[5];
    const float* wqw = (const float*)d_in[6];
    const float* wqb = (const float*)d_in[7];
    const float* wvw = (const float*)d_in[8];
    const float* wvb = (const float*)d_in[9];
    float* out = (float*)d_out;
    char* ws = (char*)d_ws;
    unsigned short* abf = (unsigned short*)(ws);              // 2048*768 bf16
    unsigned short* wbf = (unsigned short*)(ws + 3145728);    // 2304*768 bf16
    unsigned short* kb  = (unsigned short*)(ws + 6684672);    // [b,h,m,e] bf16
    unsigned short* qb  = (unsigned short*)(ws + 9830400);    // [b,h,n,e] bf16 (scaled)
    unsigned short* vt  = (unsigned short*)(ws + 12976128);   // [b,h,e,m] bf16
    float*          Lt  = (float*)(ws + 16121856);            // [b,h,n,m] f32

    k_cvt <<<1824, 256, 0, stream>>>(fa, abf, wkw, wqw, wvw, wbf);
    k_proj<<< 288, 256, 0, stream>>>(abf, wbf, wkb, wqb, wvb, kb, qb, vt);
    k_wgs <<<2048, 256, 0, stream>>>(pe, wgw, wgb, kb, qb, Lt);
    k_smv <<< 512, 256, 0, stream>>>(Lt, vt, fa, out);
}